// Round 7
// baseline (345.441 us; speedup 1.0000x reference)
//
#include <hip/hip_runtime.h>
#include <math.h>

// Problem constants
#define BB 16
#define CC 64
#define HH 160
#define WW 160
#define KK 8
#define OO 64
#define AA 16
#define HWQ (HH * WW)          // 25600

typedef __attribute__((ext_vector_type(8))) short sh8;
typedef __attribute__((ext_vector_type(4))) float fx4;

__device__ inline unsigned short f2bf(float f) {
    unsigned int u = __float_as_uint(f);
    return (unsigned short)((u + 0x7FFFu + ((u >> 16) & 1u)) >> 16);
}
__device__ inline float bf2f(unsigned short h) {
    return __uint_as_float(((unsigned int)h) << 16);
}

// ---------------------------------------------------------------------------
// Kernel A: transpose x [b][c][h][w] fp32 -> xt_hi/xt_lo [b][h][w][c] bf16
// (split precision: x = hi + lo). float4 global loads, short8 global stores.
// LDS rows skewed by 4 floats per 8-row group: phase-2 read bank =
// (4g + 20e + w) mod 32 -> 2-way max (free), was 8-way at plain stride 84.
// GAP partials per (b, h-half) row; reduced in mlp_kernel (no atomics).
// ---------------------------------------------------------------------------
#define TSROW(c) ((c) * 84 + (((c) >> 3) << 2))
__global__ __launch_bounds__(256) void trans_kernel(
    const float* __restrict__ x,
    unsigned short* __restrict__ xt_hi, unsigned short* __restrict__ xt_lo,
    float* __restrict__ pg) {
    __shared__ float ts[5408];       // 21.6 KB (64 rows, skewed stride)
    const int half = blockIdx.x;     // 0..1
    const int h    = blockIdx.y;     // 0..159
    const int b    = blockIdx.z;
    const int w0   = half * 80;
    const int tid  = threadIdx.x;

    // phase 1: 64c x 80w as float4 (16B/lane)
    for (int i = tid; i < 1280; i += 256) {
        int c  = i / 20;
        int wq = i % 20;
        float4 v = *(const float4*)(
            x + (((size_t)(b * CC + c)) * HH + h) * WW + w0 + wq * 4);
        *(float4*)(&ts[TSROW(c) + wq * 4]) = v;
    }
    __syncthreads();

    // GAP partial: thread c sums its 80 w's
    if (tid < 64) {
        float s = 0.f;
        const float* row = &ts[TSROW(tid)];
        #pragma unroll 10
        for (int w = 0; w < 80; ++w) s += row[w];
        pg[((size_t)b * 320 + h * 2 + half) * 64 + tid] = s;
    }

    // phase 2: pack 8 c's per 16B store -> 1KB/wave contiguous stores
    for (int i = tid; i < 640; i += 256) {
        int g = i & 7;            // c granule
        int w = i >> 3;           // 0..79
        sh8 vh, vl;
        #pragma unroll
        for (int e = 0; e < 8; ++e) {
            float v = ts[TSROW(g * 8 + e) + w];
            unsigned short hh = f2bf(v);
            vh[e] = (short)hh;
            vl[e] = (short)f2bf(v - bf2f(hh));
        }
        size_t off = (((size_t)(b * HH + h)) * WW + w0 + w) * CC + g * 8;
        *(sh8*)(xt_hi + off) = vh;
        *(sh8*)(xt_lo + off) = vl;
    }
}

// ---------------------------------------------------------------------------
// Kernel B: GAP reduction + routing MLP + BN + 4 attention heads.
// One block per batch sample.
// ---------------------------------------------------------------------------
__global__ __launch_bounds__(128) void mlp_kernel(
    const float* __restrict__ scale,
    const float* __restrict__ rw1, const float* __restrict__ rb1,
    const float* __restrict__ rw2, const float* __restrict__ rb2,
    const float* __restrict__ fc_w,
    const float* __restrict__ bn_gamma, const float* __restrict__ bn_beta,
    const float* __restrict__ bn_mean, const float* __restrict__ bn_var,
    const float* __restrict__ cfc_w, const float* __restrict__ cfc_b,
    const float* __restrict__ ffc_w, const float* __restrict__ ffc_b,
    const float* __restrict__ sfc_w, const float* __restrict__ sfc_b,
    const float* __restrict__ kfc_w, const float* __restrict__ kfc_b,
    const float* __restrict__ pg,
    float* __restrict__ ca, float* __restrict__ fa,
    float* __restrict__ sa, float* __restrict__ ka) {
    int b = blockIdx.x;
    int t = threadIdx.x;
    __shared__ float sin_[CC + 2];
    __shared__ float h1[2 * CC];
    __shared__ float h2[CC];
    __shared__ float vv[AA];
    __shared__ float kl[KK];

    if (t < 2) sin_[t] = 1.0f / scale[t];
    if (t < CC) {
        float s = 0.f;
        #pragma unroll 8
        for (int h2v = 0; h2v < 320; ++h2v)
            s += pg[((size_t)b * 320 + h2v) * 64 + t];
        sin_[2 + t] = s * (1.0f / (float)HWQ);
    }
    __syncthreads();

    {
        float a = rb1[t];
        const float* wr = rw1 + (size_t)t * (CC + 2);
        #pragma unroll 6
        for (int j = 0; j < CC + 2; ++j) a += sin_[j] * wr[j];
        h1[t] = fmaxf(a, 0.f);
    }
    __syncthreads();

    if (t < CC) {
        float a = rb2[t];
        const float* wr = rw2 + (size_t)t * (2 * CC);
        #pragma unroll 8
        for (int j = 0; j < 2 * CC; ++j) a += h1[j] * wr[j];
        h2[t] = fmaxf(a, 0.f);
    }
    __syncthreads();

    if (t < AA) {
        float a = 0.f;
        const float* wr = fc_w + (size_t)t * CC;
        #pragma unroll 8
        for (int j = 0; j < CC; ++j) a += h2[j] * wr[j];
        a = (a - bn_mean[t]) * rsqrtf(bn_var[t] + 1e-5f) * bn_gamma[t] + bn_beta[t];
        vv[t] = fmaxf(a, 0.f);
    }
    __syncthreads();

    if (t < CC) {
        float a = cfc_b[t];
        const float* wr = cfc_w + (size_t)t * AA;
        #pragma unroll
        for (int j = 0; j < AA; ++j) a += vv[j] * wr[j];
        ca[b * CC + t] = 1.f / (1.f + expf(-a));
        float f = ffc_b[t];
        const float* wf = ffc_w + (size_t)t * AA;
        #pragma unroll
        for (int j = 0; j < AA; ++j) f += vv[j] * wf[j];
        fa[b * CC + t] = 1.f / (1.f + expf(-f));
    }
    if (t < 9) {
        float a = sfc_b[t];
        const float* wr = sfc_w + (size_t)t * AA;
        #pragma unroll
        for (int j = 0; j < AA; ++j) a += vv[j] * wr[j];
        sa[b * 16 + t] = 1.f / (1.f + expf(-a));
    }
    if (t < KK) {
        float a = kfc_b[t];
        const float* wr = kfc_w + (size_t)t * AA;
        #pragma unroll
        for (int j = 0; j < AA; ++j) a += vv[j] * wr[j];
        kl[t] = a;
    }
    __syncthreads();
    if (t < KK) {
        float m = kl[0];
        #pragma unroll
        for (int j = 1; j < KK; ++j) m = fmaxf(m, kl[j]);
        float sum = 0.f;
        #pragma unroll
        for (int j = 0; j < KK; ++j) sum += expf(kl[j] - m);
        ka[b * KK + t] = expf(kl[t] - m) / sum;
    }
}

// ---------------------------------------------------------------------------
// Kernel C: aggregate expert weights (fold ca/fa/sa), split into bf16 hi/lo,
// emitted in MFMA A-fragment lane order (step stride 2048 shorts):
//   lane = (o&15) | ((c_local>>3)<<4), elem j = c_local&7, ch = c>>5
// ---------------------------------------------------------------------------
__global__ __launch_bounds__(256) void agg_frag_kernel(
    const float* __restrict__ weight,
    const float* __restrict__ ca, const float* __restrict__ fa,
    const float* __restrict__ sa, const float* __restrict__ ka,
    unsigned short* __restrict__ Ahi, unsigned short* __restrict__ Alo) {
    int e = blockIdx.x * 256 + threadIdx.x;   // < 16*64*64*9 = 589824
    int q  = e % 9;
    int t2 = e / 9;
    int c  = t2 & 63;
    int bo = t2 >> 6;
    int o  = bo & 63;
    int b  = bo >> 6;
    float s = 0.f;
    #pragma unroll
    for (int k = 0; k < KK; ++k)
        s += ka[b * KK + k] * weight[(((size_t)(k * OO + o)) * CC + c) * 9 + q];
    float val = s * sa[b * 16 + q] * ca[b * CC + c] * fa[b * CC + o];
    unsigned short hi = f2bf(val);
    unsigned short lo = f2bf(val - bf2f(hi));
    int mt = o >> 4;
    int lane = (o & 15) | (((c >> 3) & 3) << 4);
    int j = c & 7;
    int ch = c >> 5;
    size_t off = ((((size_t)(b * 9 + q) * 2 + ch) * 4 + mt) * 64 + lane) * 8 + j;
    Ahi[off] = hi;
    Alo[off] = lo;
}

// ---------------------------------------------------------------------------
// Kernel D: per-sample 3x3 conv via split-bf16 MFMA (implicit GEMM).
// Block = 4 waves = 8 output rows x 16 w x 64 o; wave = 2 rows (nr).
// 18 K-steps (9 q x 2 ch); per step: 8 global A-frag loads + 4 LDS B reads
// feed 24 MFMAs. Register double-buffer (next-step A and B prefetched) to
// hide L2/LDS latency at the LDS-capped 3 waves/SIMD occupancy;
// __launch_bounds__(256,3) frees VGPR headroom (~170 cap) for the pipeline.
// acc += Ahi*Bhi + Ahi*Blo + Alo*Bhi  (dropped Alo*Blo ~ 2^-16 relative).
// ---------------------------------------------------------------------------
__global__ __launch_bounds__(256, 3) void conv_mfma_kernel(
    const unsigned short* __restrict__ xt_hi,
    const unsigned short* __restrict__ xt_lo,
    const unsigned short* __restrict__ Ahi,
    const unsigned short* __restrict__ Alo,
    float* __restrict__ out) {
    __shared__ __align__(16) unsigned short xs_hi[10 * 18 * 64];
    __shared__ __align__(16) unsigned short xs_lo[10 * 18 * 64];

    const int b  = blockIdx.z;
    const int h0 = blockIdx.y * 8;
    const int w0 = blockIdx.x * 16;
    const int tid  = threadIdx.x;
    const int wv   = tid >> 6;        // wave id -> rows 2wv, 2wv+1
    const int lane = tid & 63;

    // ---- stage x tile: rows h0-1..h0+8, cols w0-1..w0+16, all 64 c ----
    for (int i = tid; i < 10 * 18 * 8; i += 256) {
        int g   = i & 7;
        int col = (i >> 3) % 18;
        int row = i / 144;
        int gh = h0 - 1 + row;
        int gw = w0 - 1 + col;
        uint4 vhi = {0u, 0u, 0u, 0u}, vlo = {0u, 0u, 0u, 0u};
        if ((unsigned)gh < (unsigned)HH && (unsigned)gw < (unsigned)WW) {
            size_t off = (((size_t)(b * HH + gh)) * WW + gw) * CC + g * 8;
            vhi = *(const uint4*)(xt_hi + off);
            vlo = *(const uint4*)(xt_lo + off);
        }
        int lidx = (row * 18 + col) * 64 + ((g ^ (col & 7)) << 3);
        *(uint4*)(&xs_hi[lidx]) = vhi;
        *(uint4*)(&xs_lo[lidx]) = vlo;
    }
    __syncthreads();

    fx4 z = {0.f, 0.f, 0.f, 0.f};
    fx4 acc[2][4] = {{z, z, z, z}, {z, z, z, z}};

    const int lr = lane & 15;         // A row (o within 16) / B col (px)
    const int l4 = lane >> 4;         // k-subblock 0..3

    const unsigned short* Ah = Ahi + (size_t)b * 36864 + lane * 8;
    const unsigned short* Al = Alo + (size_t)b * 36864 + lane * 8;

    // B-fragment LDS index for K-step s, row-offset nr
    auto bofs = [&](int s, int nr) -> int {
        int q = s >> 1, ch = s & 1;
        int kh = q / 3, kw = q % 3;
        int col = lr + kw;
        int row = wv * 2 + nr + kh;
        int g = ch * 4 + l4;
        return (row * 18 + col) * 64 + ((g ^ (col & 7)) << 3);
    };

    // prime the register pipeline (step 0)
    sh8 cah[4], cal[4], cbh[2], cbl[2];
    #pragma unroll
    for (int mt = 0; mt < 4; ++mt) {
        cah[mt] = *(const sh8*)(Ah + mt * 512);
        cal[mt] = *(const sh8*)(Al + mt * 512);
    }
    #pragma unroll
    for (int nr = 0; nr < 2; ++nr) {
        int li = bofs(0, nr);
        cbh[nr] = *(const sh8*)(&xs_hi[li]);
        cbl[nr] = *(const sh8*)(&xs_lo[li]);
    }

    #pragma unroll
    for (int s = 0; s < 18; ++s) {
        sh8 nah[4], nal[4], nbh[2], nbl[2];
        if (s < 17) {
            #pragma unroll
            for (int mt = 0; mt < 4; ++mt) {
                nah[mt] = *(const sh8*)(Ah + (s + 1) * 2048 + mt * 512);
                nal[mt] = *(const sh8*)(Al + (s + 1) * 2048 + mt * 512);
            }
            #pragma unroll
            for (int nr = 0; nr < 2; ++nr) {
                int li = bofs(s + 1, nr);
                nbh[nr] = *(const sh8*)(&xs_hi[li]);
                nbl[nr] = *(const sh8*)(&xs_lo[li]);
            }
        }
        // 24 MFMAs as 3 layers of 8 independent chains
        #pragma unroll
        for (int nr = 0; nr < 2; ++nr)
            #pragma unroll
            for (int mt = 0; mt < 4; ++mt)
                acc[nr][mt] = __builtin_amdgcn_mfma_f32_16x16x32_bf16(
                    cah[mt], cbh[nr], acc[nr][mt], 0, 0, 0);
        #pragma unroll
        for (int nr = 0; nr < 2; ++nr)
            #pragma unroll
            for (int mt = 0; mt < 4; ++mt)
                acc[nr][mt] = __builtin_amdgcn_mfma_f32_16x16x32_bf16(
                    cah[mt], cbl[nr], acc[nr][mt], 0, 0, 0);
        #pragma unroll
        for (int nr = 0; nr < 2; ++nr)
            #pragma unroll
            for (int mt = 0; mt < 4; ++mt)
                acc[nr][mt] = __builtin_amdgcn_mfma_f32_16x16x32_bf16(
                    cal[mt], cbh[nr], acc[nr][mt], 0, 0, 0);
        if (s < 17) {
            #pragma unroll
            for (int mt = 0; mt < 4; ++mt) { cah[mt] = nah[mt]; cal[mt] = nal[mt]; }
            #pragma unroll
            for (int nr = 0; nr < 2; ++nr) { cbh[nr] = nbh[nr]; cbl[nr] = nbl[nr]; }
        }
    }

    // ---- epilogue: D layout col=lane&15 (px), row=(lane>>4)*4+reg (o) ----
    #pragma unroll
    for (int nr = 0; nr < 2; ++nr) {
        const int hrow = h0 + wv * 2 + nr;
        #pragma unroll
        for (int mt = 0; mt < 4; ++mt) {
            #pragma unroll
            for (int jj = 0; jj < 4; ++jj) {
                int o = mt * 16 + l4 * 4 + jj;
                out[((size_t)(b * OO + o)) * HWQ + hrow * WW + w0 + lr] =
                    acc[nr][mt][jj];
            }
        }
    }
}

// ---------------------------------------------------------------------------
extern "C" void kernel_launch(void* const* d_in, const int* in_sizes, int n_in,
                              void* d_out, int out_size, void* d_ws, size_t ws_size,
                              hipStream_t stream) {
    const float* x        = (const float*)d_in[0];
    const float* scale    = (const float*)d_in[1];
    const float* rw1      = (const float*)d_in[2];
    const float* rb1      = (const float*)d_in[3];
    const float* rw2      = (const float*)d_in[4];
    const float* rb2      = (const float*)d_in[5];
    const float* fc_w     = (const float*)d_in[6];
    const float* bn_gamma = (const float*)d_in[7];
    const float* bn_beta  = (const float*)d_in[8];
    const float* bn_mean  = (const float*)d_in[9];
    const float* bn_var   = (const float*)d_in[10];
    const float* cfc_w    = (const float*)d_in[11];
    const float* cfc_b    = (const float*)d_in[12];
    const float* ffc_w    = (const float*)d_in[13];
    const float* ffc_b    = (const float*)d_in[14];
    const float* sfc_w    = (const float*)d_in[15];
    const float* sfc_b    = (const float*)d_in[16];
    const float* kfc_w    = (const float*)d_in[17];
    const float* kfc_b    = (const float*)d_in[18];
    const float* weight   = (const float*)d_in[19];

    // workspace layout (bytes):
    //   [0)        ca/fa/sa/ka small vectors (16 KB)
    //   [16384)    Ahi [16384,1196032), Alo [1196032,2375680)
    //              pg (16*320*64 f32 = 1310720 B) ALIASES [16384,1327104):
    //              trans writes -> mlp reads -> agg clobbers (stream-ordered).
    //   [2375680)  xt_hi 26214400 bf16 (52428800 B)
    //   [54804480) xt_lo 26214400 bf16
    //   total = 107233280 B (proven sufficient in rounds 5-6)
    const size_t WS_NEEDED = 107233280u;
    if (ws_size < WS_NEEDED) return;  // fail cleanly, don't crash

    char* wsb = (char*)d_ws;
    float* ca  = (float*)(wsb + 0);
    float* fa  = (float*)(wsb + 4096);
    float* sa  = (float*)(wsb + 8192);
    float* ka  = (float*)(wsb + 12288);
    float* pg  = (float*)(wsb + 16384);
    unsigned short* Ahi  = (unsigned short*)(wsb + 16384);
    unsigned short* Alo  = (unsigned short*)(wsb + 1196032);
    unsigned short* xthi = (unsigned short*)(wsb + 2375680);
    unsigned short* xtlo = (unsigned short*)(wsb + 54804480);

    trans_kernel<<<dim3(2, 160, 16), dim3(256), 0, stream>>>(
        x, xthi, xtlo, pg);
    mlp_kernel<<<dim3(BB), dim3(128), 0, stream>>>(
        scale, rw1, rb1, rw2, rb2, fc_w, bn_gamma, bn_beta, bn_mean, bn_var,
        cfc_w, cfc_b, ffc_w, ffc_b, sfc_w, sfc_b, kfc_w, kfc_b,
        pg, ca, fa, sa, ka);
    agg_frag_kernel<<<dim3(589824 / 256), dim3(256), 0, stream>>>(
        weight, ca, fa, sa, ka, Ahi, Alo);
    conv_mfma_kernel<<<dim3(10, 20, 16), dim3(256), 0, stream>>>(
        xthi, xtlo, Ahi, Alo, (float*)d_out);
}